// Round 6
// baseline (415.984 us; speedup 1.0000x reference)
//
#include <hip/hip_runtime.h>

#define HH 96
#define WW 96
#define CC 21
#define BB 2
#define NN (HH*WW)          // 9216
#define NT16 (NN/16)        // 576 sorted 16-tiles per batch
#define NJB  (NN/32)        // 288 j-blocks per batch
#define CHK 8               // kept-jblocks per wave slot
#define SLOT8 36            // ceil(NJB/CHK)
#define NBILB (BB*NT16*SLOT8/4)   // 10368 bilateral blocks (4 wave-slots each)
#define PRUNE_T 24.0f       // exp2-domain skip threshold
#define GST 104             // LDS row stride for 96-wide bf16 rows

// feature pre-scale folds 1/2 and log2(e): k = exp2(-sum(diff^2))
#define KSA2 (0.84932184f / 160.0f)   // bilateral spatial
#define KSB2 (0.84932184f / 3.0f)     // bilateral color
#define GL2  (1.44269504f / 18.0f)    // spatial kernel exp(-d^2/18) in exp2 units

typedef __attribute__((ext_vector_type(4))) float f32x4;
typedef __attribute__((ext_vector_type(8))) short short8;
typedef __attribute__((ext_vector_type(4))) int int4v;

static __device__ inline unsigned pk_bf16(float a, float b) {
    unsigned ua = __builtin_bit_cast(unsigned, a);
    unsigned ub = __builtin_bit_cast(unsigned, b);
    ua += 0x7FFF + ((ua >> 16) & 1);
    ub += 0x7FFF + ((ub >> 16) & 1);
    return (ua >> 16) | (ub & 0xFFFF0000u);
}
static __device__ inline unsigned short bf16_1(float a) {
    unsigned ua = __builtin_bit_cast(unsigned, a);
    ua += 0x7FFF + ((ua >> 16) & 1);
    return (unsigned short)(ua >> 16);
}

// ---------------- P0: tables + constant smht rows + zero hist (fused) ------
__global__ __launch_bounds__(256) void prep_kernel(
    float* __restrict__ sxt, unsigned short* __restrict__ gbt,
    unsigned short* __restrict__ smht, int* __restrict__ gh)
{
    int idx = blockIdx.x * 256 + threadIdx.x;
    if (idx < BB * 11 * NN) {
        int b = idx / (11 * NN);
        int rem = idx - b * 11 * NN;
        int r = rem / NN, col = rem - r * NN;
        smht[(size_t)(b * 32 + 21 + r) * NN + col] = (r == 0) ? 0x3F80 : 0;
    }
    if (idx < BB * 4096) gh[idx] = 0;
    if (blockIdx.x == 0) {
        __shared__ float gt[96];
        int t = threadIdx.x;
        if (t < 96) gt[t] = __builtin_amdgcn_exp2f(-(float)(t * t) * GL2);
        __syncthreads();
        if (t < 96) {
            float s = 0.f;
            for (int v = 0; v < 96; v++) s += gt[abs(t - v)];
            sxt[t] = s;
            for (int v = 0; v < 96; v++) gbt[t * 96 + v] = bf16_1(gt[abs(t - v)]);
        }
    }
}

// ---------------- P1: parallel counting sort by 12-bit color cell ----------
__global__ __launch_bounds__(256) void hist_kernel(
    const float* __restrict__ rgb, int* __restrict__ gh)
{
    int idx = blockIdx.x * 256 + threadIdx.x;
    if (idx >= BB * NN) return;
    int b = idx / NN;
    const float* rp = rgb + (size_t)idx * 3;
    int cr = min(15, (int)rp[0] >> 4);
    int cg = min(15, (int)rp[1] >> 4);
    int cb = min(15, (int)rp[2] >> 4);
    atomicAdd(&gh[b * 4096 + ((cr << 8) | (cg << 4) | cb)], 1);
}

__global__ __launch_bounds__(256) void scan_kernel(
    const int* __restrict__ gh, int* __restrict__ goff)
{
    __shared__ int ps[256];
    int t = threadIdx.x;
    for (int b = 0; b < BB; b++) {
        int base = b * 4096 + t * 16;
        int loc[16], s = 0;
#pragma unroll
        for (int k = 0; k < 16; k++) { loc[k] = gh[base + k]; s += loc[k]; }
        ps[t] = s;
        __syncthreads();
        for (int off = 1; off < 256; off <<= 1) {
            int add = (t >= off) ? ps[t - off] : 0;
            __syncthreads();
            ps[t] += add;
            __syncthreads();
        }
        int run = ps[t] - s;
#pragma unroll
        for (int k = 0; k < 16; k++) { goff[base + k] = run; run += loc[k]; }
        __syncthreads();
    }
}

__global__ __launch_bounds__(256) void scatter_kernel(
    const float* __restrict__ rgb, int* __restrict__ goff,
    int* __restrict__ spos, float* __restrict__ fjs)
{
    int idx = blockIdx.x * 256 + threadIdx.x;
    if (idx >= BB * NN) return;
    int b = idx / NN, p = idx - b * NN;
    const float* rp = rgb + (size_t)idx * 3;
    float r = rp[0], g = rp[1], bl = rp[2];
    int cr = min(15, (int)r >> 4);
    int cg = min(15, (int)g >> 4);
    int cb = min(15, (int)bl >> 4);
    int pos = atomicAdd(&goff[b * 4096 + ((cr << 8) | (cg << 4) | cb)], 1);
    spos[idx] = pos;
    int y = p / WW, x = p - y * WW;
    float* fb = fjs + (size_t)b * 5 * NN;
    fb[0 * NN + pos] = r * KSB2;
    fb[1 * NN + pos] = g * KSB2;
    fb[2 * NN + pos] = bl * KSB2;
    fb[3 * NN + pos] = (float)y * KSA2;
    fb[4 * NN + pos] = (float)x * KSA2;
}

// ---------------- P2a: color bbox per sorted 16-tile -----------------------
__global__ __launch_bounds__(256) void bounds_kernel(
    const float* __restrict__ fjs, float* __restrict__ bnd)
{
    int idx = blockIdx.x * 256 + threadIdx.x;
    if (idx >= BB * NT16) return;
    int b = idx / NT16, tile = idx - b * NT16;
    const float* fb = fjs + (size_t)b * 5 * NN + tile * 16;
    float lo[3], hi[3];
#pragma unroll
    for (int f = 0; f < 3; f++) { lo[f] = 1e30f; hi[f] = -1e30f; }
    for (int k = 0; k < 16; k++) {
#pragma unroll
        for (int f = 0; f < 3; f++) {
            float v = fb[f * NN + k];
            lo[f] = fminf(lo[f], v); hi[f] = fmaxf(hi[f], v);
        }
    }
    float* o = bnd + (size_t)idx * 6;
#pragma unroll
    for (int f = 0; f < 3; f++) { o[2 * f] = lo[f]; o[2 * f + 1] = hi[f]; }
}

// ---------------- P2b: fused mask + compact kept-jblock list ---------------
// one thread per (b, tile16); loop over 288 jblocks is lane-broadcast reads
__global__ __launch_bounds__(256) void maskchunks_kernel(
    const float* __restrict__ bnd, unsigned short* __restrict__ jlist,
    int* __restrict__ cnt)
{
    int bt = blockIdx.x * 256 + threadIdx.x;
    if (bt >= BB * NT16) return;
    int b = bt / NT16;
    const float* tb = bnd + (size_t)bt * 6;
    float tlo0 = tb[0], thi0 = tb[1], tlo1 = tb[2], thi1 = tb[3], tlo2 = tb[4], thi2 = tb[5];
    unsigned short* jl = jlist + (size_t)bt * NJB;
    int n = 0;
    const float* bb = bnd + (size_t)b * NT16 * 6;
    for (int jb = 0; jb < NJB; jb++) {
        const float* a0 = bb + (size_t)(2 * jb) * 6;
        float s = 0.f;
#pragma unroll
        for (int f = 0; f < 3; f++) {
            float jlo = fminf(a0[2 * f], a0[6 + 2 * f]);
            float jhi = fmaxf(a0[2 * f + 1], a0[6 + 2 * f + 1]);
            float lo = (f == 0) ? tlo0 : (f == 1) ? tlo1 : tlo2;
            float hi = (f == 0) ? thi0 : (f == 1) ? thi1 : thi2;
            float gap = fmaxf(0.f, fmaxf(lo - jhi, jlo - hi));
            s = fmaf(gap, gap, s);
        }
        if (s <= PRUNE_T) jl[n++] = (unsigned short)jb;
    }
    cnt[bt] = n;
}

// ---------------- K1: per-pixel softmax (iteration 0) ----------------------
__global__ __launch_bounds__(256) void softmax_kernel(
    const float* __restrict__ q, const int* __restrict__ spos,
    unsigned short* __restrict__ smpb, unsigned short* __restrict__ smht,
    float* __restrict__ part)
{
    int idx = blockIdx.x * 256 + threadIdx.x;
    if (idx >= BB * NN) return;
    int b = idx / NN, p = idx - b * NN;
    const float* qp = q + (size_t)idx * CC;
    float v[CC], m = -1e30f;
#pragma unroll
    for (int c = 0; c < CC; c++) { v[c] = qp[c]; m = fmaxf(m, v[c]); }
    float ssum = 0.f;
#pragma unroll
    for (int c = 0; c < CC; c++) { v[c] = __expf(v[c] - m); ssum += v[c]; }
    float inv = 1.0f / ssum;
    int s = spos[idx];
#pragma unroll
    for (int c = 0; c < CC; c++) {
        unsigned short h = bf16_1(v[c] * inv);
        smpb[(size_t)(b * CC + c) * NN + p] = h;
        smht[(size_t)(b * 32 + c) * NN + s] = h;
    }
    float* pp = part + (size_t)(b * NN + s) * 24;
#pragma unroll
    for (int k = 0; k < 24; k++) pp[k] = 0.f;
}

// ---------------- bilateral helpers (depth-2 pipelined j-set) --------------
struct JSet { float vf[5][8]; short8 sb0, sb1; };

static __device__ __forceinline__ void load_jset(
    JSet& s, const float* __restrict__ fb, const unsigned short* __restrict__ smb,
    int jb, int quad, int l16)
{
    int coff = jb * 32 + quad * 8;
#pragma unroll
    for (int f = 0; f < 5; f++) {
        const float4* pf = (const float4*)(fb + (size_t)f * NN + coff);
        float4 lo = pf[0], hi = pf[1];
        s.vf[f][0] = lo.x; s.vf[f][1] = lo.y; s.vf[f][2] = lo.z; s.vf[f][3] = lo.w;
        s.vf[f][4] = hi.x; s.vf[f][5] = hi.y; s.vf[f][6] = hi.z; s.vf[f][7] = hi.w;
    }
    s.sb0 = *(const short8*)(smb + (size_t)l16 * NN + coff);
    s.sb1 = *(const short8*)(smb + (size_t)(16 + l16) * NN + coff);
}

static __device__ __forceinline__ void compute_jset(
    const JSet& s, float fi0, float fi1, float fi2, float fi3, float fi4,
    f32x4& acc0, f32x4& acc1)
{
    float kf[8];
#pragma unroll
    for (int e = 0; e < 8; e++) {
        float d0 = s.vf[0][e] - fi0;
        float d1 = s.vf[1][e] - fi1;
        float d2 = s.vf[2][e] - fi2;
        float d3 = s.vf[3][e] - fi3;
        float d4 = s.vf[4][e] - fi4;
        float sm = d0 * d0;
        sm = fmaf(d1, d1, sm);
        sm = fmaf(d2, d2, sm);
        sm = fmaf(d3, d3, sm);
        sm = fmaf(d4, d4, sm);
        kf[e] = __builtin_amdgcn_exp2f(-sm);
    }
    int4v ap = { (int)pk_bf16(kf[0], kf[1]), (int)pk_bf16(kf[2], kf[3]),
                 (int)pk_bf16(kf[4], kf[5]), (int)pk_bf16(kf[6], kf[7]) };
    short8 afrag = __builtin_bit_cast(short8, ap);
    acc0 = __builtin_amdgcn_mfma_f32_16x16x32_bf16(afrag, s.sb0, acc0, 0, 0, 0);
    acc1 = __builtin_amdgcn_mfma_f32_16x16x32_bf16(afrag, s.sb1, acc1, 0, 0, 0);
}

// ---------------- K2: FUSED spatial conv (blocks 0..41) + bilateral --------
__global__ __launch_bounds__(256) void conv_bil_kernel(
    const unsigned short* __restrict__ smpb, const unsigned short* __restrict__ gbt,
    const float* __restrict__ sxt, float* __restrict__ spf,
    const unsigned short* __restrict__ smht, const float* __restrict__ fjs,
    const unsigned short* __restrict__ jlist, const int* __restrict__ cntv,
    float* __restrict__ part)
{
    __shared__ unsigned short C1t[96 * GST];   // 20 KB (conv path only)
    int tid = threadIdx.x;
    int lane = tid & 63, w = tid >> 6;
    int quad = lane >> 4, l16 = lane & 15;

    if (blockIdx.x < BB * CC) {
        // ================= conv path: SP = G @ P @ G =================
        int bc = blockIdx.x;
        const unsigned short* plane = smpb + (size_t)bc * NN;
        for (int mt = w; mt < 6; mt += 4) {
            int m0 = mt * 16;
            short8 a[3];
#pragma unroll
            for (int kk = 0; kk < 3; kk++)
                a[kk] = *(const short8*)(plane + (size_t)(m0 + l16) * 96 + kk * 32 + quad * 8);
            f32x4 acc[6];
#pragma unroll
            for (int nt = 0; nt < 6; nt++) acc[nt] = (f32x4){0.f, 0.f, 0.f, 0.f};
#pragma unroll
            for (int nt = 0; nt < 6; nt++) {
#pragma unroll
                for (int kk = 0; kk < 3; kk++) {
                    short8 bf = *(const short8*)(gbt + (nt * 16 + l16) * 96 + kk * 32 + quad * 8);
                    acc[nt] = __builtin_amdgcn_mfma_f32_16x16x32_bf16(a[kk], bf, acc[nt], 0, 0, 0);
                }
            }
#pragma unroll
            for (int nt = 0; nt < 6; nt++) {
                unsigned* dst = (unsigned*)&C1t[(nt * 16 + l16) * GST + m0 + quad * 4];
                dst[0] = pk_bf16(acc[nt][0], acc[nt][1]);
                dst[1] = pk_bf16(acc[nt][2], acc[nt][3]);
            }
        }
        __syncthreads();
        float* outp = spf + (size_t)bc * NN;
        for (int mt = w; mt < 6; mt += 4) {
            int m0 = mt * 16;
            short8 a[3];
#pragma unroll
            for (int kk = 0; kk < 3; kk++)
                a[kk] = *(const short8*)(gbt + (m0 + l16) * 96 + kk * 32 + quad * 8);
            f32x4 acc[6];
#pragma unroll
            for (int nt = 0; nt < 6; nt++) acc[nt] = (f32x4){0.f, 0.f, 0.f, 0.f};
#pragma unroll
            for (int nt = 0; nt < 6; nt++) {
#pragma unroll
                for (int kk = 0; kk < 3; kk++) {
                    short8 bf = *(const short8*)&C1t[(nt * 16 + l16) * GST + kk * 32 + quad * 8];
                    acc[nt] = __builtin_amdgcn_mfma_f32_16x16x32_bf16(a[kk], bf, acc[nt], 0, 0, 0);
                }
            }
#pragma unroll
            for (int nt = 0; nt < 6; nt++) {
                int x = nt * 16 + l16;
                float sx = sxt[x];
#pragma unroll
                for (int r = 0; r < 4; r++) {
                    int y = m0 + quad * 4 + r;
                    float invn = __builtin_amdgcn_rcpf(sxt[y] * sx);
                    outp[y * 96 + x] = acc[nt][r] * invn;
                }
            }
        }
        return;
    }

    // ================= bilateral path: one wave per CHK-chunk =================
    int slot = (blockIdx.x - BB * CC) * 4 + w;
    int bt = slot / SLOT8;
    int ck = slot - bt * SLOT8;
    int cnt = cntv[bt] - ck * CHK;
    if (cnt <= 0) return;
    cnt = min(cnt, CHK);
    int b = bt / NT16, tile16 = bt - b * NT16;
    int i = tile16 * 16 + l16;
    const float* fb = fjs + (size_t)b * 5 * NN;
    float fi0 = fb[0 * NN + i], fi1 = fb[1 * NN + i], fi2 = fb[2 * NN + i];
    float fi3 = fb[3 * NN + i], fi4 = fb[4 * NN + i];
    f32x4 acc0 = {0.f, 0.f, 0.f, 0.f};
    f32x4 acc1 = {0.f, 0.f, 0.f, 0.f};
    const unsigned short* smb = smht + (size_t)b * 32 * NN;
    const unsigned short* jl = jlist + (size_t)bt * NJB + ck * CHK;

    JSet A, B;
    load_jset(A, fb, smb, jl[0], quad, l16);
    int k = 0;
    while (true) {
        if (k + 1 < cnt) load_jset(B, fb, smb, jl[k + 1], quad, l16);
        compute_jset(A, fi0, fi1, fi2, fi3, fi4, acc0, acc1);
        if (++k >= cnt) break;
        if (k + 1 < cnt) load_jset(A, fb, smb, jl[k + 1], quad, l16);
        compute_jset(B, fi0, fi1, fi2, fi3, fi4, acc0, acc1);
        if (++k >= cnt) break;
    }

    int ibase = tile16 * 16 + quad * 4;
    float* pr = part + (size_t)b * NN * 24;
#pragma unroll
    for (int r = 0; r < 4; r++)
        atomicAdd(&pr[(size_t)(ibase + r) * 24 + l16], acc0[r]);
    if (l16 < 6) {
#pragma unroll
        for (int r = 0; r < 4; r++)
            atomicAdd(&pr[(size_t)(ibase + r) * 24 + 16 + l16], acc1[r]);
    }
}

// ------- K3: norm + messages + update, fused with next iter's softmax ------
__global__ __launch_bounds__(256) void update_fused_kernel(
    const float* __restrict__ u, const float* __restrict__ spf,
    float* __restrict__ part, const int* __restrict__ spos,
    const float* __restrict__ Ws, const float* __restrict__ Wb,
    const float* __restrict__ M, float* __restrict__ qout,
    unsigned short* __restrict__ smpb, unsigned short* __restrict__ smht, int wr)
{
    __shared__ float sWs[441], sWb[441], sM[441];
    for (int t = threadIdx.x; t < 441; t += 256) {
        sWs[t] = Ws[t]; sWb[t] = Wb[t]; sM[t] = M[t];
    }
    __syncthreads();
    int idx = blockIdx.x * 256 + threadIdx.x;
    if (idx >= BB * NN) return;
    int b = idx / NN, p = idx - b * NN;
    int s = spos[idx];
    float* pp = part + (size_t)(b * NN + s) * 24;
    float blv[22];
#pragma unroll
    for (int c = 0; c < 22; c++) blv[c] = pp[c];
    float ninv = 1.0f / blv[21];
    float spv[CC], msg[CC];
#pragma unroll
    for (int c = 0; c < CC; c++) {
        blv[c] *= ninv;
        spv[c] = spf[(size_t)(b * CC + c) * NN + p];
    }
#pragma unroll
    for (int c = 0; c < CC; c++) {
        float a = 0.f;
        const float* wr2 = &sWs[c * CC];
        const float* br = &sWb[c * CC];
#pragma unroll
        for (int c2 = 0; c2 < CC; c2++) a = fmaf(wr2[c2], spv[c2], a);
#pragma unroll
        for (int c2 = 0; c2 < CC; c2++) a = fmaf(br[c2], blv[c2], a);
        msg[c] = a;
    }
    const float* up = u + (size_t)idx * CC;
    float* qp = qout + (size_t)idx * CC;
    float qv[CC];
#pragma unroll
    for (int c = 0; c < CC; c++) {
        float a = up[c];
        const float* mr = &sM[c * CC];
#pragma unroll
        for (int c2 = 0; c2 < CC; c2++) a = fmaf(-mr[c2], msg[c2], a);
        qv[c] = a;
        qp[c] = a;
    }
    if (wr) {
        float m = -1e30f;
#pragma unroll
        for (int c = 0; c < CC; c++) m = fmaxf(m, qv[c]);
        float ssum = 0.f;
#pragma unroll
        for (int c = 0; c < CC; c++) { qv[c] = __expf(qv[c] - m); ssum += qv[c]; }
        float inv = 1.0f / ssum;
#pragma unroll
        for (int c = 0; c < CC; c++) {
            unsigned short h = bf16_1(qv[c] * inv);
            smpb[(size_t)(b * CC + c) * NN + p] = h;
            smht[(size_t)(b * 32 + c) * NN + s] = h;
        }
#pragma unroll
        for (int k = 0; k < 24; k++) pp[k] = 0.f;
    }
}

extern "C" void kernel_launch(void* const* d_in, const int* in_sizes, int n_in,
                              void* d_out, int out_size, void* d_ws, size_t ws_size,
                              hipStream_t stream)
{
    const float* unary = (const float*)d_in[0];  // [B,H,W,C]
    const float* rgb   = (const float*)d_in[1];  // [B,H,W,3]
    const float* Ws    = (const float*)d_in[2];
    const float* Wb    = (const float*)d_in[3];
    const float* M     = (const float*)d_in[4];
    float* out = (float*)d_out;                  // [B,N,C]

    float* SXT  = (float*)d_ws;                            // 96
    float* FJS  = SXT + 96;                                // B*5*N
    float* SPF  = FJS + (size_t)BB * 5 * NN;               // B*21*N
    float* PART = SPF + (size_t)BB * CC * NN;              // B*N*24
    float* BND  = PART + (size_t)BB * NN * 24;             // B*576*6
    int*   SPOS = (int*)(BND + (size_t)BB * NT16 * 6);     // B*N
    int*   GH   = SPOS + BB * NN;                          // B*4096
    int*   GOFF = GH + BB * 4096;                          // B*4096
    int*   CNT  = GOFF + BB * 4096;                        // B*576
    unsigned short* JL = (unsigned short*)(CNT + BB * NT16);  // B*576*288
    unsigned short* SMHT = JL + (size_t)BB * NT16 * NJB;   // B*32*N
    unsigned short* SMPB = SMHT + (size_t)BB * 32 * NN;    // B*21*N
    unsigned short* GBT  = SMPB + (size_t)BB * CC * NN;    // 96*96

    prep_kernel<<<(BB * 11 * NN + 255) / 256, 256, 0, stream>>>(SXT, GBT, SMHT, GH);
    hist_kernel<<<(BB * NN + 255) / 256, 256, 0, stream>>>(rgb, GH);
    scan_kernel<<<1, 256, 0, stream>>>(GH, GOFF);
    scatter_kernel<<<(BB * NN + 255) / 256, 256, 0, stream>>>(rgb, GOFF, SPOS, FJS);
    bounds_kernel<<<(BB * NT16 + 255) / 256, 256, 0, stream>>>(FJS, BND);
    maskchunks_kernel<<<(BB * NT16 + 255) / 256, 256, 0, stream>>>(BND, JL, CNT);

    softmax_kernel<<<(BB * NN + 255) / 256, 256, 0, stream>>>(unary, SPOS, SMPB, SMHT, PART);
    for (int it = 0; it < 5; ++it) {
        conv_bil_kernel<<<BB * CC + NBILB, 256, 0, stream>>>(
            SMPB, GBT, SXT, SPF, SMHT, FJS, JL, CNT, PART);
        update_fused_kernel<<<(BB * NN + 255) / 256, 256, 0, stream>>>(
            unary, SPF, PART, SPOS, Ws, Wb, M, out, SMPB, SMHT, (it < 4) ? 1 : 0);
    }
}

// Round 7
// 355.079 us; speedup vs baseline: 1.1715x; 1.1715x over previous
//
#include <hip/hip_runtime.h>

#define HH 96
#define WW 96
#define CC 21
#define BB 2
#define NN (HH*WW)          // 9216
#define NT16 (NN/16)        // 576 sorted 16-tiles per batch
#define NJB  (NN/32)        // 288 j-blocks per batch
#define CHK 8               // kept-jblocks per worklist slot
#define NBILB 1296          // fixed bilateral grid (5184 waves, grid-stride)
#define PRUNE_T 24.0f       // exp2-domain skip threshold
#define GST 104             // LDS row stride for 96-wide bf16 rows

// feature pre-scale folds 1/2 and log2(e): k = exp2(-sum(diff^2))
#define KSA2 (0.84932184f / 160.0f)   // bilateral spatial
#define KSB2 (0.84932184f / 3.0f)     // bilateral color
#define GL2  (1.44269504f / 18.0f)    // spatial kernel exp(-d^2/18) in exp2 units

typedef __attribute__((ext_vector_type(4))) float f32x4;
typedef __attribute__((ext_vector_type(8))) short short8;
typedef __attribute__((ext_vector_type(4))) int int4v;

static __device__ inline unsigned pk_bf16(float a, float b) {
    unsigned ua = __builtin_bit_cast(unsigned, a);
    unsigned ub = __builtin_bit_cast(unsigned, b);
    ua += 0x7FFF + ((ua >> 16) & 1);
    ub += 0x7FFF + ((ub >> 16) & 1);
    return (ua >> 16) | (ub & 0xFFFF0000u);
}
static __device__ inline unsigned short bf16_1(float a) {
    unsigned ua = __builtin_bit_cast(unsigned, a);
    ua += 0x7FFF + ((ua >> 16) & 1);
    return (unsigned short)(ua >> 16);
}

// ---------------- P0: tables + constant smht rows + zero hist + zero wlc ---
__global__ __launch_bounds__(256) void prep_kernel(
    float* __restrict__ sxt, unsigned short* __restrict__ gbt,
    unsigned short* __restrict__ smht, int* __restrict__ gh, int* __restrict__ wlc)
{
    int idx = blockIdx.x * 256 + threadIdx.x;
    if (idx == 0) wlc[0] = 0;
    if (idx < BB * 11 * NN) {
        int b = idx / (11 * NN);
        int rem = idx - b * 11 * NN;
        int r = rem / NN, col = rem - r * NN;
        smht[(size_t)(b * 32 + 21 + r) * NN + col] = (r == 0) ? 0x3F80 : 0;
    }
    if (idx < BB * 4096) gh[idx] = 0;
    if (blockIdx.x == 0) {
        __shared__ float gt[96];
        int t = threadIdx.x;
        if (t < 96) gt[t] = __builtin_amdgcn_exp2f(-(float)(t * t) * GL2);
        __syncthreads();
        if (t < 96) {
            float s = 0.f;
            for (int v = 0; v < 96; v++) s += gt[abs(t - v)];
            sxt[t] = s;
            for (int v = 0; v < 96; v++) gbt[t * 96 + v] = bf16_1(gt[abs(t - v)]);
        }
    }
}

// ---------------- P1: parallel counting sort by 12-bit color cell ----------
__global__ __launch_bounds__(256) void hist_kernel(
    const float* __restrict__ rgb, int* __restrict__ gh)
{
    int idx = blockIdx.x * 256 + threadIdx.x;
    if (idx >= BB * NN) return;
    int b = idx / NN;
    const float* rp = rgb + (size_t)idx * 3;
    int cr = min(15, (int)rp[0] >> 4);
    int cg = min(15, (int)rp[1] >> 4);
    int cb = min(15, (int)rp[2] >> 4);
    atomicAdd(&gh[b * 4096 + ((cr << 8) | (cg << 4) | cb)], 1);
}

__global__ __launch_bounds__(256) void scan_kernel(
    const int* __restrict__ gh, int* __restrict__ goff)
{
    __shared__ int ps[256];
    int t = threadIdx.x;
    for (int b = 0; b < BB; b++) {
        int base = b * 4096 + t * 16;
        int loc[16], s = 0;
#pragma unroll
        for (int k = 0; k < 16; k++) { loc[k] = gh[base + k]; s += loc[k]; }
        ps[t] = s;
        __syncthreads();
        for (int off = 1; off < 256; off <<= 1) {
            int add = (t >= off) ? ps[t - off] : 0;
            __syncthreads();
            ps[t] += add;
            __syncthreads();
        }
        int run = ps[t] - s;
#pragma unroll
        for (int k = 0; k < 16; k++) { goff[base + k] = run; run += loc[k]; }
        __syncthreads();
    }
}

__global__ __launch_bounds__(256) void scatter_kernel(
    const float* __restrict__ rgb, int* __restrict__ goff,
    int* __restrict__ spos, float* __restrict__ fjs)
{
    int idx = blockIdx.x * 256 + threadIdx.x;
    if (idx >= BB * NN) return;
    int b = idx / NN, p = idx - b * NN;
    const float* rp = rgb + (size_t)idx * 3;
    float r = rp[0], g = rp[1], bl = rp[2];
    int cr = min(15, (int)r >> 4);
    int cg = min(15, (int)g >> 4);
    int cb = min(15, (int)bl >> 4);
    int pos = atomicAdd(&goff[b * 4096 + ((cr << 8) | (cg << 4) | cb)], 1);
    spos[idx] = pos;
    int y = p / WW, x = p - y * WW;
    float* fb = fjs + (size_t)b * 5 * NN;
    fb[0 * NN + pos] = r * KSB2;
    fb[1 * NN + pos] = g * KSB2;
    fb[2 * NN + pos] = bl * KSB2;
    fb[3 * NN + pos] = (float)y * KSA2;
    fb[4 * NN + pos] = (float)x * KSA2;
}

// ---------------- P2a: color bbox per sorted 16-tile -----------------------
__global__ __launch_bounds__(256) void bounds_kernel(
    const float* __restrict__ fjs, float* __restrict__ bnd)
{
    int idx = blockIdx.x * 256 + threadIdx.x;
    if (idx >= BB * NT16) return;
    int b = idx / NT16, tile = idx - b * NT16;
    const float* fb = fjs + (size_t)b * 5 * NN + tile * 16;
    float lo[3], hi[3];
#pragma unroll
    for (int f = 0; f < 3; f++) { lo[f] = 1e30f; hi[f] = -1e30f; }
    for (int k = 0; k < 16; k++) {
#pragma unroll
        for (int f = 0; f < 3; f++) {
            float v = fb[f * NN + k];
            lo[f] = fminf(lo[f], v); hi[f] = fmaxf(hi[f], v);
        }
    }
    float* o = bnd + (size_t)idx * 6;
#pragma unroll
    for (int f = 0; f < 3; f++) { o[2 * f] = lo[f]; o[2 * f + 1] = hi[f]; }
}

// ------ P2b: wave-parallel mask + ballot-compact jlist + emit worklist -----
// one WAVE per (b, tile16); 5 rounds of 64 jblocks; slot entries -> WL.
__global__ __launch_bounds__(256) void maskchunks_kernel(
    const float* __restrict__ bnd, unsigned short* __restrict__ jlist,
    int* __restrict__ cnt, int* __restrict__ wl, int* __restrict__ wlc)
{
    int lane = threadIdx.x & 63;
    int bt = blockIdx.x * 4 + (threadIdx.x >> 6);
    if (bt >= BB * NT16) return;
    int b = bt / NT16;
    const float* tb = bnd + (size_t)bt * 6;
    float tlo0 = tb[0], thi0 = tb[1], tlo1 = tb[2], thi1 = tb[3], tlo2 = tb[4], thi2 = tb[5];
    unsigned short* jl = jlist + (size_t)bt * NJB;
    const float* bb = bnd + (size_t)b * NT16 * 6;
    int n = 0;
#pragma unroll
    for (int r = 0; r < 5; r++) {
        int jb = r * 64 + lane;
        bool keep = false;
        if (jb < NJB) {
            const float* a0 = bb + (size_t)(2 * jb) * 6;
            float s = 0.f;
#pragma unroll
            for (int f = 0; f < 3; f++) {
                float jlo = fminf(a0[2 * f], a0[6 + 2 * f]);
                float jhi = fmaxf(a0[2 * f + 1], a0[6 + 2 * f + 1]);
                float lo = (f == 0) ? tlo0 : (f == 1) ? tlo1 : tlo2;
                float hi = (f == 0) ? thi0 : (f == 1) ? thi1 : thi2;
                float gap = fmaxf(0.f, fmaxf(lo - jhi, jlo - hi));
                s = fmaf(gap, gap, s);
            }
            keep = (s <= PRUNE_T);
        }
        unsigned long long m = __ballot(keep);
        if (keep) {
            int pre = __popcll(m & ((1ull << lane) - 1ull));
            jl[n + pre] = (unsigned short)jb;
        }
        n += __popcll(m);
    }
    if (lane == 0) {
        cnt[bt] = n;
        int nsl = (n + CHK - 1) / CHK;
        if (nsl > 0) {
            int base = atomicAdd(wlc, nsl);
            for (int s2 = 0; s2 < nsl; s2++) wl[base + s2] = bt * 64 + s2;
        }
    }
}

// ---------------- K1: per-pixel softmax (iteration 0) ----------------------
__global__ __launch_bounds__(256) void softmax_kernel(
    const float* __restrict__ q, const int* __restrict__ spos,
    unsigned short* __restrict__ smpb, unsigned short* __restrict__ smht,
    float* __restrict__ part)
{
    int idx = blockIdx.x * 256 + threadIdx.x;
    if (idx >= BB * NN) return;
    int b = idx / NN, p = idx - b * NN;
    const float* qp = q + (size_t)idx * CC;
    float v[CC], m = -1e30f;
#pragma unroll
    for (int c = 0; c < CC; c++) { v[c] = qp[c]; m = fmaxf(m, v[c]); }
    float ssum = 0.f;
#pragma unroll
    for (int c = 0; c < CC; c++) { v[c] = __expf(v[c] - m); ssum += v[c]; }
    float inv = 1.0f / ssum;
    int s = spos[idx];
#pragma unroll
    for (int c = 0; c < CC; c++) {
        unsigned short h = bf16_1(v[c] * inv);
        smpb[(size_t)(b * CC + c) * NN + p] = h;
        smht[(size_t)(b * 32 + c) * NN + s] = h;
    }
    float* pp = part + (size_t)(b * NN + s) * 24;
#pragma unroll
    for (int k = 0; k < 24; k++) pp[k] = 0.f;
}

// ---------------- K2a: spatial conv = G @ P @ G via MFMA, one plane/block --
__global__ __launch_bounds__(256) void conv_kernel(
    const unsigned short* __restrict__ smpb, const unsigned short* __restrict__ gbt,
    const float* __restrict__ sxt, float* __restrict__ spf)
{
    __shared__ unsigned short C1t[96 * GST];
    int tid = threadIdx.x;
    int lane = tid & 63, w = tid >> 6;
    int quad = lane >> 4, l16 = lane & 15;
    int bc = blockIdx.x;
    const unsigned short* plane = smpb + (size_t)bc * NN;
    for (int mt = w; mt < 6; mt += 4) {
        int m0 = mt * 16;
        short8 a[3];
#pragma unroll
        for (int kk = 0; kk < 3; kk++)
            a[kk] = *(const short8*)(plane + (size_t)(m0 + l16) * 96 + kk * 32 + quad * 8);
        f32x4 acc[6];
#pragma unroll
        for (int nt = 0; nt < 6; nt++) acc[nt] = (f32x4){0.f, 0.f, 0.f, 0.f};
#pragma unroll
        for (int nt = 0; nt < 6; nt++) {
#pragma unroll
            for (int kk = 0; kk < 3; kk++) {
                short8 bf = *(const short8*)(gbt + (nt * 16 + l16) * 96 + kk * 32 + quad * 8);
                acc[nt] = __builtin_amdgcn_mfma_f32_16x16x32_bf16(a[kk], bf, acc[nt], 0, 0, 0);
            }
        }
#pragma unroll
        for (int nt = 0; nt < 6; nt++) {
            unsigned* dst = (unsigned*)&C1t[(nt * 16 + l16) * GST + m0 + quad * 4];
            dst[0] = pk_bf16(acc[nt][0], acc[nt][1]);
            dst[1] = pk_bf16(acc[nt][2], acc[nt][3]);
        }
    }
    __syncthreads();
    float* outp = spf + (size_t)bc * NN;
    for (int mt = w; mt < 6; mt += 4) {
        int m0 = mt * 16;
        short8 a[3];
#pragma unroll
        for (int kk = 0; kk < 3; kk++)
            a[kk] = *(const short8*)(gbt + (m0 + l16) * 96 + kk * 32 + quad * 8);
        f32x4 acc[6];
#pragma unroll
        for (int nt = 0; nt < 6; nt++) acc[nt] = (f32x4){0.f, 0.f, 0.f, 0.f};
#pragma unroll
        for (int nt = 0; nt < 6; nt++) {
#pragma unroll
            for (int kk = 0; kk < 3; kk++) {
                short8 bf = *(const short8*)&C1t[(nt * 16 + l16) * GST + kk * 32 + quad * 8];
                acc[nt] = __builtin_amdgcn_mfma_f32_16x16x32_bf16(a[kk], bf, acc[nt], 0, 0, 0);
            }
        }
#pragma unroll
        for (int nt = 0; nt < 6; nt++) {
            int x = nt * 16 + l16;
            float sx = sxt[x];
#pragma unroll
            for (int r = 0; r < 4; r++) {
                int y = m0 + quad * 4 + r;
                float invn = __builtin_amdgcn_rcpf(sxt[y] * sx);
                outp[y * 96 + x] = acc[nt][r] * invn;
            }
        }
    }
}

// ---------------- bilateral helpers (depth-2 pipelined j-set) --------------
struct JSet { float vf[5][8]; short8 sb0, sb1; };

static __device__ __forceinline__ void load_jset(
    JSet& s, const float* __restrict__ fb, const unsigned short* __restrict__ smb,
    int jb, int quad, int l16)
{
    int coff = jb * 32 + quad * 8;
#pragma unroll
    for (int f = 0; f < 5; f++) {
        const float4* pf = (const float4*)(fb + (size_t)f * NN + coff);
        float4 lo = pf[0], hi = pf[1];
        s.vf[f][0] = lo.x; s.vf[f][1] = lo.y; s.vf[f][2] = lo.z; s.vf[f][3] = lo.w;
        s.vf[f][4] = hi.x; s.vf[f][5] = hi.y; s.vf[f][6] = hi.z; s.vf[f][7] = hi.w;
    }
    s.sb0 = *(const short8*)(smb + (size_t)l16 * NN + coff);
    s.sb1 = *(const short8*)(smb + (size_t)(16 + l16) * NN + coff);
}

static __device__ __forceinline__ void compute_jset(
    const JSet& s, float fi0, float fi1, float fi2, float fi3, float fi4,
    f32x4& acc0, f32x4& acc1)
{
    float kf[8];
#pragma unroll
    for (int e = 0; e < 8; e++) {
        float d0 = s.vf[0][e] - fi0;
        float d1 = s.vf[1][e] - fi1;
        float d2 = s.vf[2][e] - fi2;
        float d3 = s.vf[3][e] - fi3;
        float d4 = s.vf[4][e] - fi4;
        float sm = d0 * d0;
        sm = fmaf(d1, d1, sm);
        sm = fmaf(d2, d2, sm);
        sm = fmaf(d3, d3, sm);
        sm = fmaf(d4, d4, sm);
        kf[e] = __builtin_amdgcn_exp2f(-sm);
    }
    int4v ap = { (int)pk_bf16(kf[0], kf[1]), (int)pk_bf16(kf[2], kf[3]),
                 (int)pk_bf16(kf[4], kf[5]), (int)pk_bf16(kf[6], kf[7]) };
    short8 afrag = __builtin_bit_cast(short8, ap);
    acc0 = __builtin_amdgcn_mfma_f32_16x16x32_bf16(afrag, s.sb0, acc0, 0, 0, 0);
    acc1 = __builtin_amdgcn_mfma_f32_16x16x32_bf16(afrag, s.sb1, acc1, 0, 0, 0);
}

// ---------------- K2b: bilateral over dense worklist -----------------------
// Fixed grid; each wave grid-strides over WL entries (bt, ck). Every resident
// wave has real work -> occupancy is useful occupancy.
__global__ __launch_bounds__(256) void bilateral_wl_kernel(
    const unsigned short* __restrict__ smht, const float* __restrict__ fjs,
    const unsigned short* __restrict__ jlist, const int* __restrict__ cntv,
    const int* __restrict__ wl, const int* __restrict__ wlc,
    float* __restrict__ part)
{
    int tid = threadIdx.x;
    int lane = tid & 63, w = tid >> 6;
    int quad = lane >> 4, l16 = lane & 15;
    int nwl = wlc[0];
    int totw = gridDim.x * 4;
    for (int widx = blockIdx.x * 4 + w; widx < nwl; widx += totw) {
        int e = wl[widx];
        int bt = e >> 6, ck = e & 63;
        int cnt = min(cntv[bt] - ck * CHK, CHK);
        int b = bt / NT16, tile16 = bt - b * NT16;
        int i = tile16 * 16 + l16;
        const float* fb = fjs + (size_t)b * 5 * NN;
        float fi0 = fb[0 * NN + i], fi1 = fb[1 * NN + i], fi2 = fb[2 * NN + i];
        float fi3 = fb[3 * NN + i], fi4 = fb[4 * NN + i];
        f32x4 acc0 = {0.f, 0.f, 0.f, 0.f};
        f32x4 acc1 = {0.f, 0.f, 0.f, 0.f};
        const unsigned short* smb = smht + (size_t)b * 32 * NN;
        const unsigned short* jl = jlist + (size_t)bt * NJB + ck * CHK;

        JSet A, B;
        load_jset(A, fb, smb, jl[0], quad, l16);
        int k = 0;
        while (true) {
            if (k + 1 < cnt) load_jset(B, fb, smb, jl[k + 1], quad, l16);
            compute_jset(A, fi0, fi1, fi2, fi3, fi4, acc0, acc1);
            if (++k >= cnt) break;
            if (k + 1 < cnt) load_jset(A, fb, smb, jl[k + 1], quad, l16);
            compute_jset(B, fi0, fi1, fi2, fi3, fi4, acc0, acc1);
            if (++k >= cnt) break;
        }

        int ibase = tile16 * 16 + quad * 4;
        float* pr = part + (size_t)b * NN * 24;
#pragma unroll
        for (int r = 0; r < 4; r++)
            atomicAdd(&pr[(size_t)(ibase + r) * 24 + l16], acc0[r]);
        if (l16 < 6) {
#pragma unroll
            for (int r = 0; r < 4; r++)
                atomicAdd(&pr[(size_t)(ibase + r) * 24 + 16 + l16], acc1[r]);
        }
    }
}

// ------- K3: norm + messages + update, fused with next iter's softmax ------
__global__ __launch_bounds__(256) void update_fused_kernel(
    const float* __restrict__ u, const float* __restrict__ spf,
    float* __restrict__ part, const int* __restrict__ spos,
    const float* __restrict__ Ws, const float* __restrict__ Wb,
    const float* __restrict__ M, float* __restrict__ qout,
    unsigned short* __restrict__ smpb, unsigned short* __restrict__ smht, int wr)
{
    __shared__ float sWs[441], sWb[441], sM[441];
    for (int t = threadIdx.x; t < 441; t += 256) {
        sWs[t] = Ws[t]; sWb[t] = Wb[t]; sM[t] = M[t];
    }
    __syncthreads();
    int idx = blockIdx.x * 256 + threadIdx.x;
    if (idx >= BB * NN) return;
    int b = idx / NN, p = idx - b * NN;
    int s = spos[idx];
    float* pp = part + (size_t)(b * NN + s) * 24;
    float blv[22];
#pragma unroll
    for (int c = 0; c < 22; c++) blv[c] = pp[c];
    float ninv = 1.0f / blv[21];
    float spv[CC], msg[CC];
#pragma unroll
    for (int c = 0; c < CC; c++) {
        blv[c] *= ninv;
        spv[c] = spf[(size_t)(b * CC + c) * NN + p];
    }
#pragma unroll
    for (int c = 0; c < CC; c++) {
        float a = 0.f;
        const float* wr2 = &sWs[c * CC];
        const float* br = &sWb[c * CC];
#pragma unroll
        for (int c2 = 0; c2 < CC; c2++) a = fmaf(wr2[c2], spv[c2], a);
#pragma unroll
        for (int c2 = 0; c2 < CC; c2++) a = fmaf(br[c2], blv[c2], a);
        msg[c] = a;
    }
    const float* up = u + (size_t)idx * CC;
    float* qp = qout + (size_t)idx * CC;
    float qv[CC];
#pragma unroll
    for (int c = 0; c < CC; c++) {
        float a = up[c];
        const float* mr = &sM[c * CC];
#pragma unroll
        for (int c2 = 0; c2 < CC; c2++) a = fmaf(-mr[c2], msg[c2], a);
        qv[c] = a;
        qp[c] = a;
    }
    if (wr) {
        float m = -1e30f;
#pragma unroll
        for (int c = 0; c < CC; c++) m = fmaxf(m, qv[c]);
        float ssum = 0.f;
#pragma unroll
        for (int c = 0; c < CC; c++) { qv[c] = __expf(qv[c] - m); ssum += qv[c]; }
        float inv = 1.0f / ssum;
#pragma unroll
        for (int c = 0; c < CC; c++) {
            unsigned short h = bf16_1(qv[c] * inv);
            smpb[(size_t)(b * CC + c) * NN + p] = h;
            smht[(size_t)(b * 32 + c) * NN + s] = h;
        }
#pragma unroll
        for (int k = 0; k < 24; k++) pp[k] = 0.f;
    }
}

extern "C" void kernel_launch(void* const* d_in, const int* in_sizes, int n_in,
                              void* d_out, int out_size, void* d_ws, size_t ws_size,
                              hipStream_t stream)
{
    const float* unary = (const float*)d_in[0];  // [B,H,W,C]
    const float* rgb   = (const float*)d_in[1];  // [B,H,W,3]
    const float* Ws    = (const float*)d_in[2];
    const float* Wb    = (const float*)d_in[3];
    const float* M     = (const float*)d_in[4];
    float* out = (float*)d_out;                  // [B,N,C]

    float* SXT  = (float*)d_ws;                            // 96
    float* FJS  = SXT + 96;                                // B*5*N
    float* SPF  = FJS + (size_t)BB * 5 * NN;               // B*21*N
    float* PART = SPF + (size_t)BB * CC * NN;              // B*N*24
    float* BND  = PART + (size_t)BB * NN * 24;             // B*576*6
    int*   SPOS = (int*)(BND + (size_t)BB * NT16 * 6);     // B*N
    int*   GH   = SPOS + BB * NN;                          // B*4096
    int*   GOFF = GH + BB * 4096;                          // B*4096
    int*   CNT  = GOFF + BB * 4096;                        // B*576
    int*   WLC  = CNT + BB * NT16;                         // 1
    int*   WL   = WLC + 1;                                 // <= B*576*36
    unsigned short* JL = (unsigned short*)(WL + BB * NT16 * 36);  // B*576*288
    unsigned short* SMHT = JL + (size_t)BB * NT16 * NJB;   // B*32*N
    unsigned short* SMPB = SMHT + (size_t)BB * 32 * NN;    // B*21*N
    unsigned short* GBT  = SMPB + (size_t)BB * CC * NN;    // 96*96

    prep_kernel<<<(BB * 11 * NN + 255) / 256, 256, 0, stream>>>(SXT, GBT, SMHT, GH, WLC);
    hist_kernel<<<(BB * NN + 255) / 256, 256, 0, stream>>>(rgb, GH);
    scan_kernel<<<1, 256, 0, stream>>>(GH, GOFF);
    scatter_kernel<<<(BB * NN + 255) / 256, 256, 0, stream>>>(rgb, GOFF, SPOS, FJS);
    bounds_kernel<<<(BB * NT16 + 255) / 256, 256, 0, stream>>>(FJS, BND);
    maskchunks_kernel<<<(BB * NT16 + 3) / 4, 256, 0, stream>>>(BND, JL, CNT, WL, WLC);

    softmax_kernel<<<(BB * NN + 255) / 256, 256, 0, stream>>>(unary, SPOS, SMPB, SMHT, PART);
    for (int it = 0; it < 5; ++it) {
        conv_kernel<<<BB * CC, 256, 0, stream>>>(SMPB, GBT, SXT, SPF);
        bilateral_wl_kernel<<<NBILB, 256, 0, stream>>>(SMHT, FJS, JL, CNT, WL, WLC, PART);
        update_fused_kernel<<<(BB * NN + 255) / 256, 256, 0, stream>>>(
            unary, SPF, PART, SPOS, Ws, Wb, M, out, SMPB, SMHT, (it < 4) ? 1 : 0);
    }
}